// Round 15
// baseline (321.007 us; speedup 1.0000x reference)
//
#include <hip/hip_runtime.h>

typedef __attribute__((ext_vector_type(8))) short bf16x8;
typedef __attribute__((ext_vector_type(4))) float f32x4;

__device__ __forceinline__ unsigned short f2bf(float f) {
  unsigned int u = __float_as_uint(f);
  u += 0x7FFF + ((u >> 16) & 1);
  return (unsigned short)(u >> 16);
}

__device__ __forceinline__ void gload_lds16(const void* g, void* l) {
  __builtin_amdgcn_global_load_lds(
      (const __attribute__((address_space(1))) unsigned int*)g,
      (__attribute__((address_space(3))) unsigned int*)l,
      16, 0, 0);
}

#define MF(a, b, c) __builtin_amdgcn_mfma_f32_16x16x32_bf16((a), (b), (c), 0, 0, 0)
#define FENCE asm volatile("" ::: "memory")

// ---------------------------------------------------------------------------
// fused cast fp32 -> bf16 for x, w_attn, w_proj in one sweep
// ---------------------------------------------------------------------------
__global__ void cast_all(const float* __restrict__ x,
                         const float* __restrict__ wa,
                         const float* __restrict__ wp,
                         unsigned short* __restrict__ xb,
                         unsigned short* __restrict__ wab,
                         unsigned short* __restrict__ wpb,
                         int n1, int n2, int n4) {
  int stride = gridDim.x * blockDim.x;
  for (int i = blockIdx.x * blockDim.x + threadIdx.x; i < n4; i += stride) {
    const float4* src;
    ushort4* dst;
    int j;
    if (i < n1)      { src = (const float4*)x,  dst = (ushort4*)xb,  j = i; }
    else if (i < n2) { src = (const float4*)wa, dst = (ushort4*)wab, j = i - n1; }
    else             { src = (const float4*)wp, dst = (ushort4*)wpb, j = i - n2; }
    float4 v = src[j];
    ushort4 o;
    o.x = f2bf(v.x); o.y = f2bf(v.y); o.z = f2bf(v.z); o.w = f2bf(v.w);
    dst[j] = o;
  }
}

// ---------------------------------------------------------------------------
// 256x256 8-phase GEMM, BK=32 (v3): round-8 ledger at halved granularity.
// LDS 64KB -> 2 blocks/CU: zero grid tail (384 blocks all resident) +
// cross-block barrier overlap. Per iter: t0=2i (db0, ph1-4), t1=2i+1 (db1,
// ph5-8). Stage regions (16KB = 2 thread-loads, split over 2 phases):
//   ph1: LOADB(0); A.db1<-t1 (c0)      ph5: LOADB(1); A.db0<-t2 (c0)
//   ph2: A.db1<-t1 (c1)                ph6: A.db0<-t2 (c1)
//   ph3: B.db0<-t2 (c0)                ph7: B.db1<-t3 (c0)
//   ph4: B.db0<-t2 (c1) + vmcnt(2)     ph8: B.db1<-t3 (c1) + vmcnt(2)
// vmcnt(2) leaves exactly the newest 2 loads in flight; every region's first
// read is behind its vmcnt + barrier; every overwrite is >=1 barrier after
// its last read (same proof as round-8). Swizzle: 64B rows, 16B-block
// cb ^= (row&3), pre-swizzled global source, same XOR on ds_read.
// ---------------------------------------------------------------------------
template<int EPI>
__global__ __launch_bounds__(512, 2)
void gemm8p(const unsigned short* __restrict__ A,
            const unsigned short* __restrict__ Bw,
            float* __restrict__ Cf,
            unsigned short* __restrict__ Qo,
            unsigned short* __restrict__ Ko,
            unsigned short* __restrict__ Vo,
            int M, int N, int K, int Lseq) {
  __shared__ unsigned short Al[2][8192];  // [db][256 rows x 32 cols]
  __shared__ unsigned short Bl[2][8192];
  const int tid = threadIdx.x;
  const int lane = tid & 63, w = tid >> 6;
  const int wm = w >> 2, wn = w & 3;
  const int g4 = lane >> 4, r16 = lane & 15;
  const long arow0 = (long)blockIdx.y * 256;
  const long brow0 = (long)blockIdx.x * 256;

#define LDA(db, mf)                                                           \
  (*(const bf16x8*)((const char*)&Al[db][0] +                                 \
                    ((wm * 128 + (mf)*16 + r16) << 6) +                       \
                    ((g4 ^ (r16 & 3)) << 4)))
#define LDB(db, nf)                                                           \
  (*(const bf16x8*)((const char*)&Bl[db][0] +                                 \
                    ((wn * 64 + (nf)*16 + r16) << 6) +                        \
                    ((g4 ^ (r16 & 3)) << 4)))

// one gload_lds per thread: half (c_) of a 16KB tile (mat 0=A,1=B)
#define STGH(mat, db, kt, c_)                                                 \
  do {                                                                        \
    const unsigned short* g_ = (mat) ? Bw : A;                                \
    long r0_ = (mat) ? brow0 : arow0;                                         \
    int off_ = ((c_) << 13) + (tid << 4);                                     \
    int row_ = off_ >> 6;                                                     \
    int cbs_ = ((off_ >> 4) & 3) ^ (row_ & 3);                                \
    gload_lds16(g_ + (r0_ + row_) * (long)K + ((kt) << 5) + cbs_ * 8,         \
                (char*)((mat) ? &Bl[db][0] : &Al[db][0]) + off_);             \
  } while (0)

  f32x4 acc[8][4];
#pragma unroll
  for (int i = 0; i < 8; ++i)
#pragma unroll
    for (int j = 0; j < 4; ++j) acc[i][j] = (f32x4){0.f, 0.f, 0.f, 0.f};

  bf16x8 b0, b1, b2, b3;

#define PH(db, q, STAGE_STMT, VMSTMT)                                         \
  do {                                                                        \
    bf16x8 a0 = LDA(db, 2*(q)), a1 = LDA(db, 2*(q)+1);                        \
    STAGE_STMT;                                                               \
    VMSTMT;                                                                   \
    FENCE; __builtin_amdgcn_s_barrier(); FENCE;                               \
    __builtin_amdgcn_s_setprio(1);                                            \
    acc[2*(q)][0]   = MF(a0, b0, acc[2*(q)][0]);                              \
    acc[2*(q)][1]   = MF(a0, b1, acc[2*(q)][1]);                              \
    acc[2*(q)][2]   = MF(a0, b2, acc[2*(q)][2]);                              \
    acc[2*(q)][3]   = MF(a0, b3, acc[2*(q)][3]);                              \
    acc[2*(q)+1][0] = MF(a1, b0, acc[2*(q)+1][0]);                            \
    acc[2*(q)+1][1] = MF(a1, b1, acc[2*(q)+1][1]);                            \
    acc[2*(q)+1][2] = MF(a1, b2, acc[2*(q)+1][2]);                            \
    acc[2*(q)+1][3] = MF(a1, b3, acc[2*(q)+1][3]);                            \
    __builtin_amdgcn_s_setprio(0);                                            \
    FENCE; __builtin_amdgcn_s_barrier(); FENCE;                               \
  } while (0)

#define LOADB(db)                                                             \
  do {                                                                        \
    b0 = LDB(db, 0); b1 = LDB(db, 1); b2 = LDB(db, 2); b3 = LDB(db, 3);       \
  } while (0)

#define VM2 asm volatile("s_waitcnt vmcnt(2)" ::: "memory")

  const int NT = K >> 5;  // 64 K-tiles of 32
  // prologue: A(0)->db0, B(0)->db0, B(1)->db1; wait A0,B0 (B1 in flight)
  STGH(0, 0, 0, 0); STGH(0, 0, 0, 1);
  STGH(1, 0, 0, 0); STGH(1, 0, 0, 1);
  STGH(1, 1, 1, 0); STGH(1, 1, 1, 1);
  VM2;
  FENCE; __builtin_amdgcn_s_barrier(); FENCE;

  for (int i = 0; i < (NT >> 1); ++i) {
    const int t1 = 2 * i + 1;
    int t2 = 2 * i + 2; if (t2 > NT - 1) t2 = NT - 1;
    int t3 = 2 * i + 3; if (t3 > NT - 1) t3 = NT - 1;
    LOADB(0);
    PH(0, 0, STGH(0, 1, t1, 0), );        // ph1
    PH(0, 1, STGH(0, 1, t1, 1), );        // ph2
    PH(0, 2, STGH(1, 0, t2, 0), );        // ph3
    PH(0, 3, STGH(1, 0, t2, 1), VM2);     // ph4
    LOADB(1);
    PH(1, 0, STGH(0, 0, t2, 0), );        // ph5
    PH(1, 1, STGH(0, 0, t2, 1), );        // ph6
    PH(1, 2, STGH(1, 1, t3, 0), );        // ph7
    PH(1, 3, STGH(1, 1, t3, 1), VM2);     // ph8
  }
  asm volatile("s_waitcnt vmcnt(0)" ::: "memory");

  const float qscale = 0.08838834764831845f;  // 1/sqrt(128) folded into Q
#pragma unroll
  for (int mf = 0; mf < 8; ++mf) {
#pragma unroll
    for (int nf = 0; nf < 4; ++nf) {
#pragma unroll
      for (int i = 0; i < 4; ++i) {
        long row = arow0 + wm * 128 + mf * 16 + 4 * g4 + i;
        long col = brow0 + wn * 64 + nf * 16 + r16;
        float v = acc[mf][nf][i];
        if (EPI == 0) {
          Cf[row * N + col] = v;
        } else {
          int which = (int)(col >> 11);
          int h = ((int)col >> 7) & 15;
          int d = (int)col & 127;
          int b = (int)(row >> 11);
          int l = (int)row & 2047;
          long bhead = (long)(b * 16 + h);
          if (which == 0)
            Qo[(bhead * Lseq + l) * 128 + d] = f2bf(v * qscale);
          else if (which == 1)
            Ko[(bhead * Lseq + l) * 128 + d] = f2bf(v);
          else
            Vo[(bhead * 128 + d) * Lseq + l] = f2bf(v);
        }
      }
    }
  }
#undef LDA
#undef LDB
#undef STGH
#undef PH
#undef LOADB
#undef VM2
}

// ---------------------------------------------------------------------------
// 2-phase 128x128 GEMM (proj). Known-correct.
// ---------------------------------------------------------------------------
template<int EPI>
__global__ __launch_bounds__(256, 4)
void gemm_bt(const unsigned short* __restrict__ A,
             const unsigned short* __restrict__ Bw,
             float* __restrict__ Cf,
             unsigned short* __restrict__ Qo,
             unsigned short* __restrict__ Ko,
             unsigned short* __restrict__ Vo,
             int M, int N, int K, int Lseq, int nbx) {
  __shared__ unsigned short As[2][128 * 32];
  __shared__ unsigned short Bs[2][128 * 32];
  const int tid = threadIdx.x;
  const int lane = tid & 63, w = tid >> 6;
  const int wm = w >> 1, wn = w & 1;
  const int g4 = lane >> 4, r16 = lane & 15;

  const int nwg = gridDim.x;
  const int cpx = nwg >> 3;
  const int bid = (blockIdx.x & 7) * cpx + (blockIdx.x >> 3);
  const long arow0 = (long)(bid / nbx) * 128;
  const long brow0 = (long)(bid % nbx) * 128;

#define STAGE_G(k0_, buf_)                                                    \
  do {                                                                        \
    _Pragma("unroll")                                                         \
    for (int c_ = 0; c_ < 2; ++c_) {                                          \
      int off_ = (w << 11) + (c_ << 10) + (lane << 4);                        \
      int row_ = off_ >> 6;                                                   \
      int cbs_ = ((off_ >> 4) & 3) ^ ((row_ >> 1) & 3);                       \
      gload_lds16(A + (arow0 + row_) * (long)K + (k0_) + cbs_ * 8,            \
                  (char*)As[buf_] + off_);                                    \
      gload_lds16(Bw + (brow0 + row_) * (long)K + (k0_) + cbs_ * 8,           \
                  (char*)Bs[buf_] + off_);                                    \
    }                                                                         \
  } while (0)

  f32x4 acc[4][4];
#pragma unroll
  for (int i = 0; i < 4; ++i)
#pragma unroll
    for (int j = 0; j < 4; ++j) acc[i][j] = (f32x4){0.f, 0.f, 0.f, 0.f};

  const int T = K >> 5;
  int cur = 0;
  STAGE_G(0, 0);

  for (int t = 0; t < T; ++t) {
    if (t < T - 1) {
      STAGE_G((t + 1) << 5, cur ^ 1);
      asm volatile("s_waitcnt vmcnt(4)" ::: "memory");
    } else {
      asm volatile("s_waitcnt vmcnt(0)" ::: "memory");
    }
    __builtin_amdgcn_s_barrier();

    const int rb = g4 ^ ((r16 >> 1) & 3);
    bf16x8 af[4], bf[4];
#pragma unroll
    for (int mf = 0; mf < 4; ++mf)
      af[mf] = *(const bf16x8*)((const char*)As[cur] +
                                ((64 * wm + 16 * mf + r16) << 6) + (rb << 4));
#pragma unroll
    for (int nf = 0; nf < 4; ++nf)
      bf[nf] = *(const bf16x8*)((const char*)Bs[cur] +
                                ((64 * wn + 16 * nf + r16) << 6) + (rb << 4));
#pragma unroll
    for (int mf = 0; mf < 4; ++mf)
#pragma unroll
      for (int nf = 0; nf < 4; ++nf)
        acc[mf][nf] = MF(af[mf], bf[nf], acc[mf][nf]);
    asm volatile("" ::: "memory");
    __builtin_amdgcn_s_barrier();
    cur ^= 1;
  }
#undef STAGE_G

  const float qscale = 0.08838834764831845f;
#pragma unroll
  for (int mf = 0; mf < 4; ++mf) {
#pragma unroll
    for (int nf = 0; nf < 4; ++nf) {
#pragma unroll
      for (int i = 0; i < 4; ++i) {
        long row = arow0 + 64 * wm + 16 * mf + 4 * g4 + i;
        long col = brow0 + 64 * wn + 16 * nf + r16;
        float v = acc[mf][nf][i];
        if (EPI == 0) {
          Cf[row * N + col] = v;
        } else {
          int which = (int)(col >> 11);
          int h = ((int)col >> 7) & 15;
          int d = (int)col & 127;
          int b = (int)(row >> 11);
          int l = (int)row & 2047;
          long bhead = (long)(b * 16 + h);
          if (which == 0)
            Qo[(bhead * Lseq + l) * 128 + d] = f2bf(v * qscale);
          else if (which == 1)
            Ko[(bhead * Lseq + l) * 128 + d] = f2bf(v);
          else
            Vo[(bhead * 128 + d) * Lseq + l] = f2bf(v);
        }
      }
    }
  }
}

// ---------------------------------------------------------------------------
// Flash attention (causal) — round-12 version (swapped QK^T, in-lane softmax,
// defer-max). Works: ~70us.
// ---------------------------------------------------------------------------
__global__ __launch_bounds__(256, 2)
void attn_fwd(const unsigned short* __restrict__ Q,
              const unsigned short* __restrict__ K,
              const unsigned short* __restrict__ Vt,
              unsigned short* __restrict__ Y, int L) {
  const int D = 128;
  const int id = blockIdx.x;
  const int g = id & 7, kk = id >> 3;
  const int bh = (g << 2) + (kk >> 5);
  const int qt = 31 - (kk & 31);
  const int tid = threadIdx.x, lane = tid & 63, w = tid >> 6;
  const int g4 = lane >> 4, r16 = lane & 15;
  const int q0 = qt * 64;

  __shared__ unsigned short Klds[2 * 64 * 128];
  __shared__ unsigned short Vlds[2 * 128 * 64];
  __shared__ unsigned short P[4][16][64];
  __shared__ float corrS[4][16];
  __shared__ float lrunS[4][16];

  const unsigned short* Qh = Q + (long)bh * L * D;
  const unsigned short* Kh = K + (long)bh * L * D;
  const unsigned short* Vh = Vt + (long)bh * D * L;

#define STAGE_TILE(kt_, buf_)                                                 \
  do {                                                                        \
    const int kbase_ = (kt_) * 64;                                            \
    _Pragma("unroll")                                                         \
    for (int r_ = 0; r_ < 4; ++r_) {                                          \
      int off_ = (tid << 4) + (r_ << 12);                                     \
      int krow_ = off_ >> 8, kcb_ = (off_ >> 4) & 15;                         \
      int kcbs_ = kcb_ ^ (krow_ & 7);                                         \
      gload_lds16(Kh + (long)(kbase_ + krow_) * 128 + kcbs_ * 8,              \
                  (char*)Klds + (buf_)*16384 + (w << 10) + (r_ << 12));       \
      int vrow_ = off_ >> 7, vcb_ = (off_ >> 4) & 7;                          \
      int vcbs_ = vcb_ ^ (vrow_ & 7);                                         \
      gload_lds16(Vh + (long)vrow_ * L + kbase_ + vcbs_ * 8,                  \
                  (char*)Vlds + (buf_)*16384 + (w << 10) + (r_ << 12));       \
    }                                                                         \
  } while (0)

  bf16x8 qf[4];
  {
    long qrow = q0 + 16 * w + r16;
#pragma unroll
    for (int ks = 0; ks < 4; ++ks)
      qf[ks] = *(const bf16x8*)(Qh + qrow * D + ks * 32 + g4 * 8);
  }
  f32x4 o[8];
#pragma unroll
  for (int j = 0; j < 8; ++j) o[j] = (f32x4){0.f, 0.f, 0.f, 0.f};
  float mrun = -1e30f, lrun = 0.f;
  const int qg = q0 + 16 * w + r16;
  char* Pl = (char*)&P[w][0][0];

  int cur = 0;
  STAGE_TILE(0, 0);

  for (int kt = 0; kt <= qt; ++kt) {
    if (kt < qt) {
      STAGE_TILE(kt + 1, cur ^ 1);
      asm volatile("s_waitcnt vmcnt(8)" ::: "memory");
    } else {
      asm volatile("s_waitcnt vmcnt(0)" ::: "memory");
    }
    __builtin_amdgcn_s_barrier();

    const char* Kl = (const char*)Klds + cur * 16384;
    const char* Vl = (const char*)Vlds + cur * 16384;

    f32x4 s[4];
#pragma unroll
    for (int nf = 0; nf < 4; ++nf) s[nf] = (f32x4){0.f, 0.f, 0.f, 0.f};
#pragma unroll
    for (int ks = 0; ks < 4; ++ks) {
#pragma unroll
      for (int nf = 0; nf < 4; ++nf) {
        int row = 16 * nf + r16;
        bf16x8 kf = *(const bf16x8*)(Kl + row * 256 +
                                     (((ks * 4 + g4) ^ (row & 7)) << 4));
        s[nf] = MF(kf, qf[ks], s[nf]);
      }
    }

    const bool diag = (kt == qt);
    float rmax = -1e30f;
#pragma unroll
    for (int nf = 0; nf < 4; ++nf)
#pragma unroll
      for (int i = 0; i < 4; ++i) {
        float t = s[nf][i];
        if (diag && (kt * 64 + 16 * nf + 4 * g4 + i) > qg) t = -1e30f;
        s[nf][i] = t;
        rmax = fmaxf(rmax, t);
      }
    rmax = fmaxf(rmax, __shfl_xor(rmax, 16));
    rmax = fmaxf(rmax, __shfl_xor(rmax, 32));

    const bool full = __any(rmax > mrun + 8.0f);
    float corr = 1.f;
    if (full) {
      float mnew = fmaxf(mrun, rmax);
      corr = __expf(mrun - mnew);
      mrun = mnew;
      if (g4 == 0) corrS[w][r16] = corr;
    }

    float rs = 0.f;
#pragma unroll
    for (int nf = 0; nf < 4; ++nf) {
      float p0 = __expf(s[nf][0] - mrun);
      float p1 = __expf(s[nf][1] - mrun);
      float p2 = __expf(s[nf][2] - mrun);
      float p3 = __expf(s[nf][3] - mrun);
      rs += (p0 + p1) + (p2 + p3);
      ushort4 pw;
      pw.x = f2bf(p0); pw.y = f2bf(p1); pw.z = f2bf(p2); pw.w = f2bf(p3);
      *(ushort4*)(Pl + r16 * 128 + (((2 * nf + (g4 >> 1)) ^ (r16 & 7)) << 4) +
                  ((g4 & 1) << 3)) = pw;
    }
    rs += __shfl_xor(rs, 16);
    rs += __shfl_xor(rs, 32);
    lrun = lrun * corr + rs;

    if (full) {
#pragma unroll
      for (int i = 0; i < 4; ++i) {
        float cb = corrS[w][4 * g4 + i];
#pragma unroll
        for (int nf2 = 0; nf2 < 8; ++nf2) o[nf2][i] *= cb;
      }
    }

#pragma unroll
    for (int ks2 = 0; ks2 < 2; ++ks2) {
      bf16x8 pf = *(const bf16x8*)(Pl + r16 * 128 +
                                   (((ks2 * 4 + g4) ^ (r16 & 7)) << 4));
#pragma unroll
      for (int nf2 = 0; nf2 < 8; ++nf2) {
        int row = 16 * nf2 + r16;
        bf16x8 vf = *(const bf16x8*)(Vl + row * 128 +
                                     (((ks2 * 4 + g4) ^ (row & 7)) << 4));
        o[nf2] = MF(pf, vf, o[nf2]);
      }
    }
    FENCE;
    __builtin_amdgcn_s_barrier();
    cur ^= 1;
  }
#undef STAGE_TILE

  if (g4 == 0) lrunS[w][r16] = lrun;
  const int b = bh >> 4, h = bh & 15;
#pragma unroll
  for (int i = 0; i < 4; ++i) {
    float linv = 1.f / lrunS[w][4 * g4 + i];
#pragma unroll
    for (int nf2 = 0; nf2 < 8; ++nf2) {
      long row = (long)b * L + q0 + 16 * w + 4 * g4 + i;
      Y[row * 2048 + h * 128 + 16 * nf2 + r16] = f2bf(o[nf2][i] * linv);
    }
  }
}

// ---------------------------------------------------------------------------
extern "C" void kernel_launch(void* const* d_in, const int* in_sizes, int n_in,
                              void* d_out, int out_size, void* d_ws,
                              size_t ws_size, hipStream_t stream) {
  const float* x = (const float*)d_in[0];
  const float* wa = (const float*)d_in[1];
  const float* wp = (const float*)d_in[2];
  float* out = (float*)d_out;
  const int B = 2, L = 2048, C = 2048;
  const int M = B * L;  // 4096

  unsigned short* xb = (unsigned short*)d_ws;
  unsigned short* wab = xb + (size_t)M * C;
  unsigned short* wpb = wab + (size_t)3 * C * C;
  unsigned short* Qb = wpb + (size_t)C * C;
  unsigned short* Kb = Qb + (size_t)M * C;
  unsigned short* Vb = Kb + (size_t)M * C;
  unsigned short* Yb = Vb + (size_t)M * C;

  const int n1 = M * C / 4;
  const int n2 = n1 + 3 * C * C / 4;
  const int n4 = n2 + C * C / 4;
  cast_all<<<2048, 256, 0, stream>>>(x, wa, wp, xb, wab, wpb, n1, n2, n4);

  // qkv: 256^2 8-phase BK=32 (2 blocks/CU, zero tail), grid 24x16
  gemm8p<1><<<dim3(3 * C / 256, M / 256), 512, 0, stream>>>(
      xb, wab, nullptr, Qb, Kb, Vb, M, 3 * C, C, L);

  // attn: QBLK=64, 4 waves, 1024 blocks (2 blocks/CU)
  attn_fwd<<<1024, 256, 0, stream>>>(Qb, Kb, Vb, Yb, L);

  // proj: 2-phase 128^2, grid 512 blocks
  gemm_bt<0><<<(M / 128) * (C / 128), 256, 0, stream>>>(
      Yb, wpb, out, nullptr, nullptr, nullptr, M, C, C, L, C / 128);
}

// Round 18
// 313.445 us; speedup vs baseline: 1.0241x; 1.0241x over previous
//
#include <hip/hip_runtime.h>

typedef __attribute__((ext_vector_type(8))) short bf16x8;
typedef __attribute__((ext_vector_type(4))) float f32x4;

__device__ __forceinline__ unsigned short f2bf(float f) {
  unsigned int u = __float_as_uint(f);
  u += 0x7FFF + ((u >> 16) & 1);
  return (unsigned short)(u >> 16);
}

__device__ __forceinline__ void gload_lds16(const void* g, void* l) {
  __builtin_amdgcn_global_load_lds(
      (const __attribute__((address_space(1))) unsigned int*)g,
      (__attribute__((address_space(3))) unsigned int*)l,
      16, 0, 0);
}

#define MF(a, b, c) __builtin_amdgcn_mfma_f32_16x16x32_bf16((a), (b), (c), 0, 0, 0)
#define FENCE asm volatile("" ::: "memory")

// ---------------------------------------------------------------------------
// fused cast fp32 -> bf16 for x, w_attn, w_proj in one sweep
// ---------------------------------------------------------------------------
__global__ void cast_all(const float* __restrict__ x,
                         const float* __restrict__ wa,
                         const float* __restrict__ wp,
                         unsigned short* __restrict__ xb,
                         unsigned short* __restrict__ wab,
                         unsigned short* __restrict__ wpb,
                         int n1, int n2, int n4) {
  int stride = gridDim.x * blockDim.x;
  for (int i = blockIdx.x * blockDim.x + threadIdx.x; i < n4; i += stride) {
    const float4* src;
    ushort4* dst;
    int j;
    if (i < n1)      { src = (const float4*)x,  dst = (ushort4*)xb,  j = i; }
    else if (i < n2) { src = (const float4*)wa, dst = (ushort4*)wab, j = i - n1; }
    else             { src = (const float4*)wp, dst = (ushort4*)wpb, j = i - n2; }
    float4 v = src[j];
    ushort4 o;
    o.x = f2bf(v.x); o.y = f2bf(v.y); o.z = f2bf(v.z); o.w = f2bf(v.w);
    dst[j] = o;
  }
}

// ---------------------------------------------------------------------------
// 256x256 8-phase GEMM, BK=32 (v3b): round-15 structure with the CORRECT
// 64B-row swizzle cb ^= (row>>1)&3 (same as the proven 2-phase gemm_bt,
// measured 0 conflicts). v3's cb ^= row&3 left each quarter-wave on half the
// bank groups -> 9.4M conflicts -> the 21% regression. Everything else
// identical: 64KB LDS -> 2 blocks/CU, zero grid tail, round-8 ledger at
// halved granularity, vmcnt(2) at ph4/ph8.
// ---------------------------------------------------------------------------
template<int EPI>
__global__ __launch_bounds__(512, 2)
void gemm8p(const unsigned short* __restrict__ A,
            const unsigned short* __restrict__ Bw,
            float* __restrict__ Cf,
            unsigned short* __restrict__ Qo,
            unsigned short* __restrict__ Ko,
            unsigned short* __restrict__ Vo,
            int M, int N, int K, int Lseq) {
  __shared__ unsigned short Al[2][8192];  // [db][256 rows x 32 cols]
  __shared__ unsigned short Bl[2][8192];
  const int tid = threadIdx.x;
  const int lane = tid & 63, w = tid >> 6;
  const int wm = w >> 2, wn = w & 3;
  const int g4 = lane >> 4, r16 = lane & 15;
  const long arow0 = (long)blockIdx.y * 256;
  const long brow0 = (long)blockIdx.x * 256;

  const int rb = g4 ^ ((r16 >> 1) & 3);   // read column-block (swizzled)

#define LDA(db, mf)                                                           \
  (*(const bf16x8*)((const char*)&Al[db][0] +                                 \
                    ((wm * 128 + (mf)*16 + r16) << 6) + (rb << 4)))
#define LDB(db, nf)                                                           \
  (*(const bf16x8*)((const char*)&Bl[db][0] +                                 \
                    ((wn * 64 + (nf)*16 + r16) << 6) + (rb << 4)))

// one gload_lds per thread: half (c_) of a 16KB tile (mat 0=A,1=B)
#define STGH(mat, db, kt, c_)                                                 \
  do {                                                                        \
    const unsigned short* g_ = (mat) ? Bw : A;                                \
    long r0_ = (mat) ? brow0 : arow0;                                         \
    int off_ = ((c_) << 13) + (tid << 4);                                     \
    int row_ = off_ >> 6;                                                     \
    int cbs_ = ((off_ >> 4) & 3) ^ ((row_ >> 1) & 3);                         \
    gload_lds16(g_ + (r0_ + row_) * (long)K + ((kt) << 5) + cbs_ * 8,         \
                (char*)((mat) ? &Bl[db][0] : &Al[db][0]) + off_);             \
  } while (0)

  f32x4 acc[8][4];
#pragma unroll
  for (int i = 0; i < 8; ++i)
#pragma unroll
    for (int j = 0; j < 4; ++j) acc[i][j] = (f32x4){0.f, 0.f, 0.f, 0.f};

  bf16x8 b0, b1, b2, b3;

#define PH(db, q, STAGE_STMT, VMSTMT)                                         \
  do {                                                                        \
    bf16x8 a0 = LDA(db, 2*(q)), a1 = LDA(db, 2*(q)+1);                        \
    STAGE_STMT;                                                               \
    VMSTMT;                                                                   \
    FENCE; __builtin_amdgcn_s_barrier(); FENCE;                               \
    __builtin_amdgcn_s_setprio(1);                                            \
    acc[2*(q)][0]   = MF(a0, b0, acc[2*(q)][0]);                              \
    acc[2*(q)][1]   = MF(a0, b1, acc[2*(q)][1]);                              \
    acc[2*(q)][2]   = MF(a0, b2, acc[2*(q)][2]);                              \
    acc[2*(q)][3]   = MF(a0, b3, acc[2*(q)][3]);                              \
    acc[2*(q)+1][0] = MF(a1, b0, acc[2*(q)+1][0]);                            \
    acc[2*(q)+1][1] = MF(a1, b1, acc[2*(q)+1][1]);                            \
    acc[2*(q)+1][2] = MF(a1, b2, acc[2*(q)+1][2]);                            \
    acc[2*(q)+1][3] = MF(a1, b3, acc[2*(q)+1][3]);                            \
    __builtin_amdgcn_s_setprio(0);                                            \
    FENCE; __builtin_amdgcn_s_barrier(); FENCE;                               \
  } while (0)

#define LOADB(db)                                                             \
  do {                                                                        \
    b0 = LDB(db, 0); b1 = LDB(db, 1); b2 = LDB(db, 2); b3 = LDB(db, 3);       \
  } while (0)

#define VM2 asm volatile("s_waitcnt vmcnt(2)" ::: "memory")

  const int NT = K >> 5;  // 64 K-tiles of 32
  // prologue: A(0)->db0, B(0)->db0, B(1)->db1; wait A0,B0 (B1 in flight)
  STGH(0, 0, 0, 0); STGH(0, 0, 0, 1);
  STGH(1, 0, 0, 0); STGH(1, 0, 0, 1);
  STGH(1, 1, 1, 0); STGH(1, 1, 1, 1);
  VM2;
  FENCE; __builtin_amdgcn_s_barrier(); FENCE;

  for (int i = 0; i < (NT >> 1); ++i) {
    const int t1 = 2 * i + 1;
    int t2 = 2 * i + 2; if (t2 > NT - 1) t2 = NT - 1;
    int t3 = 2 * i + 3; if (t3 > NT - 1) t3 = NT - 1;
    LOADB(0);
    PH(0, 0, STGH(0, 1, t1, 0), );        // ph1
    PH(0, 1, STGH(0, 1, t1, 1), );        // ph2
    PH(0, 2, STGH(1, 0, t2, 0), );        // ph3
    PH(0, 3, STGH(1, 0, t2, 1), VM2);     // ph4
    LOADB(1);
    PH(1, 0, STGH(0, 0, t2, 0), );        // ph5
    PH(1, 1, STGH(0, 0, t2, 1), );        // ph6
    PH(1, 2, STGH(1, 1, t3, 0), );        // ph7
    PH(1, 3, STGH(1, 1, t3, 1), VM2);     // ph8
  }
  asm volatile("s_waitcnt vmcnt(0)" ::: "memory");

  const float qscale = 0.08838834764831845f;  // 1/sqrt(128) folded into Q
#pragma unroll
  for (int mf = 0; mf < 8; ++mf) {
#pragma unroll
    for (int nf = 0; nf < 4; ++nf) {
#pragma unroll
      for (int i = 0; i < 4; ++i) {
        long row = arow0 + wm * 128 + mf * 16 + 4 * g4 + i;
        long col = brow0 + wn * 64 + nf * 16 + r16;
        float v = acc[mf][nf][i];
        if (EPI == 0) {
          Cf[row * N + col] = v;
        } else {
          int which = (int)(col >> 11);
          int h = ((int)col >> 7) & 15;
          int d = (int)col & 127;
          int b = (int)(row >> 11);
          int l = (int)row & 2047;
          long bhead = (long)(b * 16 + h);
          if (which == 0)
            Qo[(bhead * Lseq + l) * 128 + d] = f2bf(v * qscale);
          else if (which == 1)
            Ko[(bhead * Lseq + l) * 128 + d] = f2bf(v);
          else
            Vo[(bhead * 128 + d) * Lseq + l] = f2bf(v);
        }
      }
    }
  }
#undef LDA
#undef LDB
#undef STGH
#undef PH
#undef LOADB
#undef VM2
}

// ---------------------------------------------------------------------------
// 2-phase 128x128 GEMM (proj). Known-correct.
// ---------------------------------------------------------------------------
template<int EPI>
__global__ __launch_bounds__(256, 4)
void gemm_bt(const unsigned short* __restrict__ A,
             const unsigned short* __restrict__ Bw,
             float* __restrict__ Cf,
             unsigned short* __restrict__ Qo,
             unsigned short* __restrict__ Ko,
             unsigned short* __restrict__ Vo,
             int M, int N, int K, int Lseq, int nbx) {
  __shared__ unsigned short As[2][128 * 32];
  __shared__ unsigned short Bs[2][128 * 32];
  const int tid = threadIdx.x;
  const int lane = tid & 63, w = tid >> 6;
  const int wm = w >> 1, wn = w & 1;
  const int g4 = lane >> 4, r16 = lane & 15;

  const int nwg = gridDim.x;
  const int cpx = nwg >> 3;
  const int bid = (blockIdx.x & 7) * cpx + (blockIdx.x >> 3);
  const long arow0 = (long)(bid / nbx) * 128;
  const long brow0 = (long)(bid % nbx) * 128;

#define STAGE_G(k0_, buf_)                                                    \
  do {                                                                        \
    _Pragma("unroll")                                                         \
    for (int c_ = 0; c_ < 2; ++c_) {                                          \
      int off_ = (w << 11) + (c_ << 10) + (lane << 4);                        \
      int row_ = off_ >> 6;                                                   \
      int cbs_ = ((off_ >> 4) & 3) ^ ((row_ >> 1) & 3);                       \
      gload_lds16(A + (arow0 + row_) * (long)K + (k0_) + cbs_ * 8,            \
                  (char*)As[buf_] + off_);                                    \
      gload_lds16(Bw + (brow0 + row_) * (long)K + (k0_) + cbs_ * 8,           \
                  (char*)Bs[buf_] + off_);                                    \
    }                                                                         \
  } while (0)

  f32x4 acc[4][4];
#pragma unroll
  for (int i = 0; i < 4; ++i)
#pragma unroll
    for (int j = 0; j < 4; ++j) acc[i][j] = (f32x4){0.f, 0.f, 0.f, 0.f};

  const int T = K >> 5;
  int cur = 0;
  STAGE_G(0, 0);

  for (int t = 0; t < T; ++t) {
    if (t < T - 1) {
      STAGE_G((t + 1) << 5, cur ^ 1);
      asm volatile("s_waitcnt vmcnt(4)" ::: "memory");
    } else {
      asm volatile("s_waitcnt vmcnt(0)" ::: "memory");
    }
    __builtin_amdgcn_s_barrier();

    const int rb = g4 ^ ((r16 >> 1) & 3);
    bf16x8 af[4], bf[4];
#pragma unroll
    for (int mf = 0; mf < 4; ++mf)
      af[mf] = *(const bf16x8*)((const char*)As[cur] +
                                ((64 * wm + 16 * mf + r16) << 6) + (rb << 4));
#pragma unroll
    for (int nf = 0; nf < 4; ++nf)
      bf[nf] = *(const bf16x8*)((const char*)Bs[cur] +
                                ((64 * wn + 16 * nf + r16) << 6) + (rb << 4));
#pragma unroll
    for (int mf = 0; mf < 4; ++mf)
#pragma unroll
      for (int nf = 0; nf < 4; ++nf)
        acc[mf][nf] = MF(af[mf], bf[nf], acc[mf][nf]);
    asm volatile("" ::: "memory");
    __builtin_amdgcn_s_barrier();
    cur ^= 1;
  }
#undef STAGE_G

  const float qscale = 0.08838834764831845f;
#pragma unroll
  for (int mf = 0; mf < 4; ++mf) {
#pragma unroll
    for (int nf = 0; nf < 4; ++nf) {
#pragma unroll
      for (int i = 0; i < 4; ++i) {
        long row = arow0 + 64 * wm + 16 * mf + 4 * g4 + i;
        long col = brow0 + 64 * wn + 16 * nf + r16;
        float v = acc[mf][nf][i];
        if (EPI == 0) {
          Cf[row * N + col] = v;
        } else {
          int which = (int)(col >> 11);
          int h = ((int)col >> 7) & 15;
          int d = (int)col & 127;
          int b = (int)(row >> 11);
          int l = (int)row & 2047;
          long bhead = (long)(b * 16 + h);
          if (which == 0)
            Qo[(bhead * Lseq + l) * 128 + d] = f2bf(v * qscale);
          else if (which == 1)
            Ko[(bhead * Lseq + l) * 128 + d] = f2bf(v);
          else
            Vo[(bhead * 128 + d) * Lseq + l] = f2bf(v);
        }
      }
    }
  }
}

// ---------------------------------------------------------------------------
// Flash attention (causal) — round-12 version (swapped QK^T, in-lane softmax,
// defer-max). Works: ~70us.
// ---------------------------------------------------------------------------
__global__ __launch_bounds__(256, 2)
void attn_fwd(const unsigned short* __restrict__ Q,
              const unsigned short* __restrict__ K,
              const unsigned short* __restrict__ Vt,
              unsigned short* __restrict__ Y, int L) {
  const int D = 128;
  const int id = blockIdx.x;
  const int g = id & 7, kk = id >> 3;
  const int bh = (g << 2) + (kk >> 5);
  const int qt = 31 - (kk & 31);
  const int tid = threadIdx.x, lane = tid & 63, w = tid >> 6;
  const int g4 = lane >> 4, r16 = lane & 15;
  const int q0 = qt * 64;

  __shared__ unsigned short Klds[2 * 64 * 128];
  __shared__ unsigned short Vlds[2 * 128 * 64];
  __shared__ unsigned short P[4][16][64];
  __shared__ float corrS[4][16];
  __shared__ float lrunS[4][16];

  const unsigned short* Qh = Q + (long)bh * L * D;
  const unsigned short* Kh = K + (long)bh * L * D;
  const unsigned short* Vh = Vt + (long)bh * D * L;

#define STAGE_TILE(kt_, buf_)                                                 \
  do {                                                                        \
    const int kbase_ = (kt_) * 64;                                            \
    _Pragma("unroll")                                                         \
    for (int r_ = 0; r_ < 4; ++r_) {                                          \
      int off_ = (tid << 4) + (r_ << 12);                                     \
      int krow_ = off_ >> 8, kcb_ = (off_ >> 4) & 15;                         \
      int kcbs_ = kcb_ ^ (krow_ & 7);                                         \
      gload_lds16(Kh + (long)(kbase_ + krow_) * 128 + kcbs_ * 8,              \
                  (char*)Klds + (buf_)*16384 + (w << 10) + (r_ << 12));       \
      int vrow_ = off_ >> 7, vcb_ = (off_ >> 4) & 7;                          \
      int vcbs_ = vcb_ ^ (vrow_ & 7);                                         \
      gload_lds16(Vh + (long)vrow_ * L + kbase_ + vcbs_ * 8,                  \
                  (char*)Vlds + (buf_)*16384 + (w << 10) + (r_ << 12));       \
    }                                                                         \
  } while (0)

  bf16x8 qf[4];
  {
    long qrow = q0 + 16 * w + r16;
#pragma unroll
    for (int ks = 0; ks < 4; ++ks)
      qf[ks] = *(const bf16x8*)(Qh + qrow * D + ks * 32 + g4 * 8);
  }
  f32x4 o[8];
#pragma unroll
  for (int j = 0; j < 8; ++j) o[j] = (f32x4){0.f, 0.f, 0.f, 0.f};
  float mrun = -1e30f, lrun = 0.f;
  const int qg = q0 + 16 * w + r16;
  char* Pl = (char*)&P[w][0][0];

  int cur = 0;
  STAGE_TILE(0, 0);

  for (int kt = 0; kt <= qt; ++kt) {
    if (kt < qt) {
      STAGE_TILE(kt + 1, cur ^ 1);
      asm volatile("s_waitcnt vmcnt(8)" ::: "memory");
    } else {
      asm volatile("s_waitcnt vmcnt(0)" ::: "memory");
    }
    __builtin_amdgcn_s_barrier();

    const char* Kl = (const char*)Klds + cur * 16384;
    const char* Vl = (const char*)Vlds + cur * 16384;

    f32x4 s[4];
#pragma unroll
    for (int nf = 0; nf < 4; ++nf) s[nf] = (f32x4){0.f, 0.f, 0.f, 0.f};
#pragma unroll
    for (int ks = 0; ks < 4; ++ks) {
#pragma unroll
      for (int nf = 0; nf < 4; ++nf) {
        int row = 16 * nf + r16;
        bf16x8 kf = *(const bf16x8*)(Kl + row * 256 +
                                     (((ks * 4 + g4) ^ (row & 7)) << 4));
        s[nf] = MF(kf, qf[ks], s[nf]);
      }
    }

    const bool diag = (kt == qt);
    float rmax = -1e30f;
#pragma unroll
    for (int nf = 0; nf < 4; ++nf)
#pragma unroll
      for (int i = 0; i < 4; ++i) {
        float t = s[nf][i];
        if (diag && (kt * 64 + 16 * nf + 4 * g4 + i) > qg) t = -1e30f;
        s[nf][i] = t;
        rmax = fmaxf(rmax, t);
      }
    rmax = fmaxf(rmax, __shfl_xor(rmax, 16));
    rmax = fmaxf(rmax, __shfl_xor(rmax, 32));

    const bool full = __any(rmax > mrun + 8.0f);
    float corr = 1.f;
    if (full) {
      float mnew = fmaxf(mrun, rmax);
      corr = __expf(mrun - mnew);
      mrun = mnew;
      if (g4 == 0) corrS[w][r16] = corr;
    }

    float rs = 0.f;
#pragma unroll
    for (int nf = 0; nf < 4; ++nf) {
      float p0 = __expf(s[nf][0] - mrun);
      float p1 = __expf(s[nf][1] - mrun);
      float p2 = __expf(s[nf][2] - mrun);
      float p3 = __expf(s[nf][3] - mrun);
      rs += (p0 + p1) + (p2 + p3);
      ushort4 pw;
      pw.x = f2bf(p0); pw.y = f2bf(p1); pw.z = f2bf(p2); pw.w = f2bf(p3);
      *(ushort4*)(Pl + r16 * 128 + (((2 * nf + (g4 >> 1)) ^ (r16 & 7)) << 4) +
                  ((g4 & 1) << 3)) = pw;
    }
    rs += __shfl_xor(rs, 16);
    rs += __shfl_xor(rs, 32);
    lrun = lrun * corr + rs;

    if (full) {
#pragma unroll
      for (int i = 0; i < 4; ++i) {
        float cb = corrS[w][4 * g4 + i];
#pragma unroll
        for (int nf2 = 0; nf2 < 8; ++nf2) o[nf2][i] *= cb;
      }
    }

#pragma unroll
    for (int ks2 = 0; ks2 < 2; ++ks2) {
      bf16x8 pf = *(const bf16x8*)(Pl + r16 * 128 +
                                   (((ks2 * 4 + g4) ^ (r16 & 7)) << 4));
#pragma unroll
      for (int nf2 = 0; nf2 < 8; ++nf2) {
        int row = 16 * nf2 + r16;
        bf16x8 vf = *(const bf16x8*)(Vl + row * 128 +
                                     (((ks2 * 4 + g4) ^ (row & 7)) << 4));
        o[nf2] = MF(pf, vf, o[nf2]);
      }
    }
    FENCE;
    __builtin_amdgcn_s_barrier();
    cur ^= 1;
  }
#undef STAGE_TILE

  if (g4 == 0) lrunS[w][r16] = lrun;
  const int b = bh >> 4, h = bh & 15;
#pragma unroll
  for (int i = 0; i < 4; ++i) {
    float linv = 1.f / lrunS[w][4 * g4 + i];
#pragma unroll
    for (int nf2 = 0; nf2 < 8; ++nf2) {
      long row = (long)b * L + q0 + 16 * w + 4 * g4 + i;
      Y[row * 2048 + h * 128 + 16 * nf2 + r16] = f2bf(o[nf2][i] * linv);
    }
  }
}

// ---------------------------------------------------------------------------
extern "C" void kernel_launch(void* const* d_in, const int* in_sizes, int n_in,
                              void* d_out, int out_size, void* d_ws,
                              size_t ws_size, hipStream_t stream) {
  const float* x = (const float*)d_in[0];
  const float* wa = (const float*)d_in[1];
  const float* wp = (const float*)d_in[2];
  float* out = (float*)d_out;
  const int B = 2, L = 2048, C = 2048;
  const int M = B * L;  // 4096

  unsigned short* xb = (unsigned short*)d_ws;
  unsigned short* wab = xb + (size_t)M * C;
  unsigned short* wpb = wab + (size_t)3 * C * C;
  unsigned short* Qb = wpb + (size_t)C * C;
  unsigned short* Kb = Qb + (size_t)M * C;
  unsigned short* Vb = Kb + (size_t)M * C;
  unsigned short* Yb = Vb + (size_t)M * C;

  const int n1 = M * C / 4;
  const int n2 = n1 + 3 * C * C / 4;
  const int n4 = n2 + C * C / 4;
  cast_all<<<2048, 256, 0, stream>>>(x, wa, wp, xb, wab, wpb, n1, n2, n4);

  // qkv: 256^2 8-phase BK=32 (2 blocks/CU, zero tail), grid 24x16
  gemm8p<1><<<dim3(3 * C / 256, M / 256), 512, 0, stream>>>(
      xb, wab, nullptr, Qb, Kb, Vb, M, 3 * C, C, L);

  // attn: QBLK=64, 4 waves, 1024 blocks (2 blocks/CU)
  attn_fwd<<<1024, 256, 0, stream>>>(Qb, Kb, Vb, Yb, L);

  // proj: 2-phase 128^2, grid 512 blocks
  gemm_bt<0><<<(M / 128) * (C / 128), 256, 0, stream>>>(
      Yb, wpb, out, nullptr, nullptr, nullptr, M, C, C, L, C / 128);
}

// Round 19
// 293.217 us; speedup vs baseline: 1.0948x; 1.0690x over previous
//
#include <hip/hip_runtime.h>

typedef __attribute__((ext_vector_type(8))) short bf16x8;
typedef __attribute__((ext_vector_type(4))) float f32x4;

__device__ __forceinline__ unsigned short f2bf(float f) {
  unsigned int u = __float_as_uint(f);
  u += 0x7FFF + ((u >> 16) & 1);
  return (unsigned short)(u >> 16);
}

__device__ __forceinline__ void gload_lds16(const void* g, void* l) {
  __builtin_amdgcn_global_load_lds(
      (const __attribute__((address_space(1))) unsigned int*)g,
      (__attribute__((address_space(3))) unsigned int*)l,
      16, 0, 0);
}

#define MF(a, b, c) __builtin_amdgcn_mfma_f32_16x16x32_bf16((a), (b), (c), 0, 0, 0)
#define FENCE asm volatile("" ::: "memory")

// ---------------------------------------------------------------------------
// fused cast fp32 -> bf16 for x, w_attn, w_proj in one sweep
// ---------------------------------------------------------------------------
__global__ void cast_all(const float* __restrict__ x,
                         const float* __restrict__ wa,
                         const float* __restrict__ wp,
                         unsigned short* __restrict__ xb,
                         unsigned short* __restrict__ wab,
                         unsigned short* __restrict__ wpb,
                         int n1, int n2, int n4) {
  int stride = gridDim.x * blockDim.x;
  for (int i = blockIdx.x * blockDim.x + threadIdx.x; i < n4; i += stride) {
    const float4* src;
    ushort4* dst;
    int j;
    if (i < n1)      { src = (const float4*)x,  dst = (ushort4*)xb,  j = i; }
    else if (i < n2) { src = (const float4*)wa, dst = (ushort4*)wab, j = i - n1; }
    else             { src = (const float4*)wp, dst = (ushort4*)wpb, j = i - n2; }
    float4 v = src[j];
    ushort4 o;
    o.x = f2bf(v.x); o.y = f2bf(v.y); o.z = f2bf(v.z); o.w = f2bf(v.w);
    dst[j] = o;
  }
}

// ---------------------------------------------------------------------------
// 128x256 4-phase GEMM (v4): round-8's proven BK=64 template with the tile
// reshaped BM 256->128 so grid = 32x24 = 768 blocks = EXACTLY 3 rounds on
// 256 CUs (round-8's 384 blocks = 1.5 rounds -> 25% tail idle). Same
// MFMA/phase (16), same barriers/FLOP, same 128B-row swizzle cb ^= row&7
// (0 conflicts measured), same counted-vmcnt discipline. LDS 96KB.
// Ledger (iter i: t0=2i from db0 ph1-2, t1=2i+1 from db1 ph3-4):
//   ph1: stage A.db1<-t1 (2)   [A.db1 last read prev ph4 top]
//   ph2: stage B.db0<-t2 (4) + vmcnt(4)  [retires B.db1(t1)+A.db1(t1)]
//   ph3: stage A.db0<-t2 (2)   [A.db0 last read ph2 top]
//   ph4: stage B.db1<-t3 (4) + vmcnt(4)  [retires B.db0(t2)+A.db0(t2)]
// Prologue: B.db0(t0) A.db0(t0) B.db1(t1) + vmcnt(4). Epilogue vmcnt(0).
// Every overwrite lands >=1 barrier after its region's last read; every
// first read is behind its vmcnt + barrier (round-8 proof carries over).
// ---------------------------------------------------------------------------
template<int EPI>
__global__ __launch_bounds__(512, 2)
void gemm8p(const unsigned short* __restrict__ A,
            const unsigned short* __restrict__ Bw,
            float* __restrict__ Cf,
            unsigned short* __restrict__ Qo,
            unsigned short* __restrict__ Ko,
            unsigned short* __restrict__ Vo,
            int M, int N, int K, int Lseq) {
  __shared__ unsigned short Al[2][128 * 64];  // 2 x 16KB
  __shared__ unsigned short Bl[2][256 * 64];  // 2 x 32KB
  const int tid = threadIdx.x;
  const int lane = tid & 63, w = tid >> 6;
  const int wm = w >> 2, wn = w & 3;          // 2 M-halves x 4 N-quarters
  const int g4 = lane >> 4, r16 = lane & 15;
  const long arow0 = (long)blockIdx.y * 128;
  const long brow0 = (long)blockIdx.x * 256;

#define LDA(db, mf, ks)                                                       \
  (*(const bf16x8*)((const char*)&Al[db][0] +                                 \
                    ((wm * 64 + (mf)*16 + r16) << 7) +                        \
                    ((((ks)*4 + g4) ^ (r16 & 7)) << 4)))
#define LDB(db, nf, ks)                                                       \
  (*(const bf16x8*)((const char*)&Bl[db][0] +                                 \
                    ((wn * 64 + (nf)*16 + r16) << 7) +                        \
                    ((((ks)*4 + g4) ^ (r16 & 7)) << 4)))

// stage A-tile (16KB, 2 issues) / B-tile (32KB, 4 issues) for K-tile kt
#define STGA(db, kt)                                                          \
  do {                                                                        \
    _Pragma("unroll")                                                         \
    for (int c_ = 0; c_ < 2; ++c_) {                                          \
      int off_ = (c_ << 13) + (tid << 4);                                     \
      int row_ = off_ >> 7;                                                   \
      int cbs_ = ((off_ >> 4) & 7) ^ (row_ & 7);                              \
      gload_lds16(A + (arow0 + row_) * (long)K + ((kt) << 6) + cbs_ * 8,      \
                  (char*)&Al[db][0] + off_);                                  \
    }                                                                         \
  } while (0)
#define STGB(db, kt)                                                          \
  do {                                                                        \
    _Pragma("unroll")                                                         \
    for (int c_ = 0; c_ < 4; ++c_) {                                          \
      int off_ = (c_ << 13) + (tid << 4);                                     \
      int row_ = off_ >> 7;                                                   \
      int cbs_ = ((off_ >> 4) & 7) ^ (row_ & 7);                              \
      gload_lds16(Bw + (brow0 + row_) * (long)K + ((kt) << 6) + cbs_ * 8,     \
                  (char*)&Bl[db][0] + off_);                                  \
    }                                                                         \
  } while (0)

  f32x4 acc[4][4];
#pragma unroll
  for (int i = 0; i < 4; ++i)
#pragma unroll
    for (int j = 0; j < 4; ++j) acc[i][j] = (f32x4){0.f, 0.f, 0.f, 0.f};

  bf16x8 b00, b01, b10, b11, b20, b21, b30, b31;  // b[nf][ks]

#define LOADB(db)                                                             \
  do {                                                                        \
    b00 = LDB(db, 0, 0); b01 = LDB(db, 0, 1);                                 \
    b10 = LDB(db, 1, 0); b11 = LDB(db, 1, 1);                                 \
    b20 = LDB(db, 2, 0); b21 = LDB(db, 2, 1);                                 \
    b30 = LDB(db, 3, 0); b31 = LDB(db, 3, 1);                                 \
  } while (0)

#define PH(db, q, STAGE_STMT, VMSTMT)                                         \
  do {                                                                        \
    bf16x8 a00 = LDA(db, 2*(q), 0), a01 = LDA(db, 2*(q), 1);                  \
    bf16x8 a10 = LDA(db, 2*(q)+1, 0), a11 = LDA(db, 2*(q)+1, 1);              \
    STAGE_STMT;                                                               \
    VMSTMT;                                                                   \
    FENCE; __builtin_amdgcn_s_barrier(); FENCE;                               \
    __builtin_amdgcn_s_setprio(1);                                            \
    acc[2*(q)][0] = MF(a00, b00, acc[2*(q)][0]);                              \
    acc[2*(q)][0] = MF(a01, b01, acc[2*(q)][0]);                              \
    acc[2*(q)][1] = MF(a00, b10, acc[2*(q)][1]);                              \
    acc[2*(q)][1] = MF(a01, b11, acc[2*(q)][1]);                              \
    acc[2*(q)][2] = MF(a00, b20, acc[2*(q)][2]);                              \
    acc[2*(q)][2] = MF(a01, b21, acc[2*(q)][2]);                              \
    acc[2*(q)][3] = MF(a00, b30, acc[2*(q)][3]);                              \
    acc[2*(q)][3] = MF(a01, b31, acc[2*(q)][3]);                              \
    acc[2*(q)+1][0] = MF(a10, b00, acc[2*(q)+1][0]);                          \
    acc[2*(q)+1][0] = MF(a11, b01, acc[2*(q)+1][0]);                          \
    acc[2*(q)+1][1] = MF(a10, b10, acc[2*(q)+1][1]);                          \
    acc[2*(q)+1][1] = MF(a11, b11, acc[2*(q)+1][1]);                          \
    acc[2*(q)+1][2] = MF(a10, b20, acc[2*(q)+1][2]);                          \
    acc[2*(q)+1][2] = MF(a11, b21, acc[2*(q)+1][2]);                          \
    acc[2*(q)+1][3] = MF(a10, b30, acc[2*(q)+1][3]);                          \
    acc[2*(q)+1][3] = MF(a11, b31, acc[2*(q)+1][3]);                          \
    __builtin_amdgcn_s_setprio(0);                                            \
    FENCE; __builtin_amdgcn_s_barrier(); FENCE;                               \
  } while (0)

#define VM4 asm volatile("s_waitcnt vmcnt(4)" ::: "memory")

  const int NT = K >> 6;  // 32 K-tiles of 64
  // prologue: B.db0(t0) A.db0(t0) B.db1(t1); vmcnt(4) leaves B.db1 in flight
  STGB(0, 0); STGA(0, 0); STGB(1, 1);
  VM4;
  FENCE; __builtin_amdgcn_s_barrier(); FENCE;

  for (int i = 0; i < (NT >> 1); ++i) {
    const int t1 = 2 * i + 1;
    int t2 = 2 * i + 2; if (t2 > NT - 1) t2 = NT - 1;
    int t3 = 2 * i + 3; if (t3 > NT - 1) t3 = NT - 1;
    LOADB(0);
    PH(0, 0, STGA(1, t1), );        // ph1
    PH(0, 1, STGB(0, t2), VM4);     // ph2
    LOADB(1);
    PH(1, 0, STGA(0, t2), );        // ph3
    PH(1, 1, STGB(1, t3), VM4);     // ph4
  }
  asm volatile("s_waitcnt vmcnt(0)" ::: "memory");

  const float qscale = 0.08838834764831845f;  // 1/sqrt(128) folded into Q
#pragma unroll
  for (int mf = 0; mf < 4; ++mf) {
#pragma unroll
    for (int nf = 0; nf < 4; ++nf) {
#pragma unroll
      for (int i = 0; i < 4; ++i) {
        long row = arow0 + wm * 64 + mf * 16 + 4 * g4 + i;
        long col = brow0 + wn * 64 + nf * 16 + r16;
        float v = acc[mf][nf][i];
        if (EPI == 0) {
          Cf[row * N + col] = v;
        } else {
          int which = (int)(col >> 11);
          int h = ((int)col >> 7) & 15;
          int d = (int)col & 127;
          int b = (int)(row >> 11);
          int l = (int)row & 2047;
          long bhead = (long)(b * 16 + h);
          if (which == 0)
            Qo[(bhead * Lseq + l) * 128 + d] = f2bf(v * qscale);
          else if (which == 1)
            Ko[(bhead * Lseq + l) * 128 + d] = f2bf(v);
          else
            Vo[(bhead * 128 + d) * Lseq + l] = f2bf(v);
        }
      }
    }
  }
#undef LDA
#undef LDB
#undef STGA
#undef STGB
#undef PH
#undef LOADB
#undef VM4
}

// ---------------------------------------------------------------------------
// 2-phase 128x128 GEMM (proj). Known-correct.
// ---------------------------------------------------------------------------
template<int EPI>
__global__ __launch_bounds__(256, 4)
void gemm_bt(const unsigned short* __restrict__ A,
             const unsigned short* __restrict__ Bw,
             float* __restrict__ Cf,
             unsigned short* __restrict__ Qo,
             unsigned short* __restrict__ Ko,
             unsigned short* __restrict__ Vo,
             int M, int N, int K, int Lseq, int nbx) {
  __shared__ unsigned short As[2][128 * 32];
  __shared__ unsigned short Bs[2][128 * 32];
  const int tid = threadIdx.x;
  const int lane = tid & 63, w = tid >> 6;
  const int wm = w >> 1, wn = w & 1;
  const int g4 = lane >> 4, r16 = lane & 15;

  const int nwg = gridDim.x;
  const int cpx = nwg >> 3;
  const int bid = (blockIdx.x & 7) * cpx + (blockIdx.x >> 3);
  const long arow0 = (long)(bid / nbx) * 128;
  const long brow0 = (long)(bid % nbx) * 128;

#define STAGE_G(k0_, buf_)                                                    \
  do {                                                                        \
    _Pragma("unroll")                                                         \
    for (int c_ = 0; c_ < 2; ++c_) {                                          \
      int off_ = (w << 11) + (c_ << 10) + (lane << 4);                        \
      int row_ = off_ >> 6;                                                   \
      int cbs_ = ((off_ >> 4) & 3) ^ ((row_ >> 1) & 3);                       \
      gload_lds16(A + (arow0 + row_) * (long)K + (k0_) + cbs_ * 8,            \
                  (char*)As[buf_] + off_);                                    \
      gload_lds16(Bw + (brow0 + row_) * (long)K + (k0_) + cbs_ * 8,           \
                  (char*)Bs[buf_] + off_);                                    \
    }                                                                         \
  } while (0)

  f32x4 acc[4][4];
#pragma unroll
  for (int i = 0; i < 4; ++i)
#pragma unroll
    for (int j = 0; j < 4; ++j) acc[i][j] = (f32x4){0.f, 0.f, 0.f, 0.f};

  const int T = K >> 5;
  int cur = 0;
  STAGE_G(0, 0);

  for (int t = 0; t < T; ++t) {
    if (t < T - 1) {
      STAGE_G((t + 1) << 5, cur ^ 1);
      asm volatile("s_waitcnt vmcnt(4)" ::: "memory");
    } else {
      asm volatile("s_waitcnt vmcnt(0)" ::: "memory");
    }
    __builtin_amdgcn_s_barrier();

    const int rb = g4 ^ ((r16 >> 1) & 3);
    bf16x8 af[4], bf[4];
#pragma unroll
    for (int mf = 0; mf < 4; ++mf)
      af[mf] = *(const bf16x8*)((const char*)As[cur] +
                                ((64 * wm + 16 * mf + r16) << 6) + (rb << 4));
#pragma unroll
    for (int nf = 0; nf < 4; ++nf)
      bf[nf] = *(const bf16x8*)((const char*)Bs[cur] +
                                ((64 * wn + 16 * nf + r16) << 6) + (rb << 4));
#pragma unroll
    for (int mf = 0; mf < 4; ++mf)
#pragma unroll
      for (int nf = 0; nf < 4; ++nf)
        acc[mf][nf] = MF(af[mf], bf[nf], acc[mf][nf]);
    asm volatile("" ::: "memory");
    __builtin_amdgcn_s_barrier();
    cur ^= 1;
  }
#undef STAGE_G

  const float qscale = 0.08838834764831845f;
#pragma unroll
  for (int mf = 0; mf < 4; ++mf) {
#pragma unroll
    for (int nf = 0; nf < 4; ++nf) {
#pragma unroll
      for (int i = 0; i < 4; ++i) {
        long row = arow0 + 64 * wm + 16 * mf + 4 * g4 + i;
        long col = brow0 + 64 * wn + 16 * nf + r16;
        float v = acc[mf][nf][i];
        if (EPI == 0) {
          Cf[row * N + col] = v;
        } else {
          int which = (int)(col >> 11);
          int h = ((int)col >> 7) & 15;
          int d = (int)col & 127;
          int b = (int)(row >> 11);
          int l = (int)row & 2047;
          long bhead = (long)(b * 16 + h);
          if (which == 0)
            Qo[(bhead * Lseq + l) * 128 + d] = f2bf(v * qscale);
          else if (which == 1)
            Ko[(bhead * Lseq + l) * 128 + d] = f2bf(v);
          else
            Vo[(bhead * 128 + d) * Lseq + l] = f2bf(v);
        }
      }
    }
  }
}

// ---------------------------------------------------------------------------
// Flash attention (causal) — round-12 version (swapped QK^T, in-lane softmax,
// defer-max). Works: ~70us.
// ---------------------------------------------------------------------------
__global__ __launch_bounds__(256, 2)
void attn_fwd(const unsigned short* __restrict__ Q,
              const unsigned short* __restrict__ K,
              const unsigned short* __restrict__ Vt,
              unsigned short* __restrict__ Y, int L) {
  const int D = 128;
  const int id = blockIdx.x;
  const int g = id & 7, kk = id >> 3;
  const int bh = (g << 2) + (kk >> 5);
  const int qt = 31 - (kk & 31);
  const int tid = threadIdx.x, lane = tid & 63, w = tid >> 6;
  const int g4 = lane >> 4, r16 = lane & 15;
  const int q0 = qt * 64;

  __shared__ unsigned short Klds[2 * 64 * 128];
  __shared__ unsigned short Vlds[2 * 128 * 64];
  __shared__ unsigned short P[4][16][64];
  __shared__ float corrS[4][16];
  __shared__ float lrunS[4][16];

  const unsigned short* Qh = Q + (long)bh * L * D;
  const unsigned short* Kh = K + (long)bh * L * D;
  const unsigned short* Vh = Vt + (long)bh * D * L;

#define STAGE_TILE(kt_, buf_)                                                 \
  do {                                                                        \
    const int kbase_ = (kt_) * 64;                                            \
    _Pragma("unroll")                                                         \
    for (int r_ = 0; r_ < 4; ++r_) {                                          \
      int off_ = (tid << 4) + (r_ << 12);                                     \
      int krow_ = off_ >> 8, kcb_ = (off_ >> 4) & 15;                         \
      int kcbs_ = kcb_ ^ (krow_ & 7);                                         \
      gload_lds16(Kh + (long)(kbase_ + krow_) * 128 + kcbs_ * 8,              \
                  (char*)Klds + (buf_)*16384 + (w << 10) + (r_ << 12));       \
      int vrow_ = off_ >> 7, vcb_ = (off_ >> 4) & 7;                          \
      int vcbs_ = vcb_ ^ (vrow_ & 7);                                         \
      gload_lds16(Vh + (long)vrow_ * L + kbase_ + vcbs_ * 8,                  \
                  (char*)Vlds + (buf_)*16384 + (w << 10) + (r_ << 12));       \
    }                                                                         \
  } while (0)

  bf16x8 qf[4];
  {
    long qrow = q0 + 16 * w + r16;
#pragma unroll
    for (int ks = 0; ks < 4; ++ks)
      qf[ks] = *(const bf16x8*)(Qh + qrow * D + ks * 32 + g4 * 8);
  }
  f32x4 o[8];
#pragma unroll
  for (int j = 0; j < 8; ++j) o[j] = (f32x4){0.f, 0.f, 0.f, 0.f};
  float mrun = -1e30f, lrun = 0.f;
  const int qg = q0 + 16 * w + r16;
  char* Pl = (char*)&P[w][0][0];

  int cur = 0;
  STAGE_TILE(0, 0);

  for (int kt = 0; kt <= qt; ++kt) {
    if (kt < qt) {
      STAGE_TILE(kt + 1, cur ^ 1);
      asm volatile("s_waitcnt vmcnt(8)" ::: "memory");
    } else {
      asm volatile("s_waitcnt vmcnt(0)" ::: "memory");
    }
    __builtin_amdgcn_s_barrier();

    const char* Kl = (const char*)Klds + cur * 16384;
    const char* Vl = (const char*)Vlds + cur * 16384;

    f32x4 s[4];
#pragma unroll
    for (int nf = 0; nf < 4; ++nf) s[nf] = (f32x4){0.f, 0.f, 0.f, 0.f};
#pragma unroll
    for (int ks = 0; ks < 4; ++ks) {
#pragma unroll
      for (int nf = 0; nf < 4; ++nf) {
        int row = 16 * nf + r16;
        bf16x8 kf = *(const bf16x8*)(Kl + row * 256 +
                                     (((ks * 4 + g4) ^ (row & 7)) << 4));
        s[nf] = MF(kf, qf[ks], s[nf]);
      }
    }

    const bool diag = (kt == qt);
    float rmax = -1e30f;
#pragma unroll
    for (int nf = 0; nf < 4; ++nf)
#pragma unroll
      for (int i = 0; i < 4; ++i) {
        float t = s[nf][i];
        if (diag && (kt * 64 + 16 * nf + 4 * g4 + i) > qg) t = -1e30f;
        s[nf][i] = t;
        rmax = fmaxf(rmax, t);
      }
    rmax = fmaxf(rmax, __shfl_xor(rmax, 16));
    rmax = fmaxf(rmax, __shfl_xor(rmax, 32));

    const bool full = __any(rmax > mrun + 8.0f);
    float corr = 1.f;
    if (full) {
      float mnew = fmaxf(mrun, rmax);
      corr = __expf(mrun - mnew);
      mrun = mnew;
      if (g4 == 0) corrS[w][r16] = corr;
    }

    float rs = 0.f;
#pragma unroll
    for (int nf = 0; nf < 4; ++nf) {
      float p0 = __expf(s[nf][0] - mrun);
      float p1 = __expf(s[nf][1] - mrun);
      float p2 = __expf(s[nf][2] - mrun);
      float p3 = __expf(s[nf][3] - mrun);
      rs += (p0 + p1) + (p2 + p3);
      ushort4 pw;
      pw.x = f2bf(p0); pw.y = f2bf(p1); pw.z = f2bf(p2); pw.w = f2bf(p3);
      *(ushort4*)(Pl + r16 * 128 + (((2 * nf + (g4 >> 1)) ^ (r16 & 7)) << 4) +
                  ((g4 & 1) << 3)) = pw;
    }
    rs += __shfl_xor(rs, 16);
    rs += __shfl_xor(rs, 32);
    lrun = lrun * corr + rs;

    if (full) {
#pragma unroll
      for (int i = 0; i < 4; ++i) {
        float cb = corrS[w][4 * g4 + i];
#pragma unroll
        for (int nf2 = 0; nf2 < 8; ++nf2) o[nf2][i] *= cb;
      }
    }

#pragma unroll
    for (int ks2 = 0; ks2 < 2; ++ks2) {
      bf16x8 pf = *(const bf16x8*)(Pl + r16 * 128 +
                                   (((ks2 * 4 + g4) ^ (r16 & 7)) << 4));
#pragma unroll
      for (int nf2 = 0; nf2 < 8; ++nf2) {
        int row = 16 * nf2 + r16;
        bf16x8 vf = *(const bf16x8*)(Vl + row * 128 +
                                     (((ks2 * 4 + g4) ^ (row & 7)) << 4));
        o[nf2] = MF(pf, vf, o[nf2]);
      }
    }
    FENCE;
    __builtin_amdgcn_s_barrier();
    cur ^= 1;
  }
#undef STAGE_TILE

  if (g4 == 0) lrunS[w][r16] = lrun;
  const int b = bh >> 4, h = bh & 15;
#pragma unroll
  for (int i = 0; i < 4; ++i) {
    float linv = 1.f / lrunS[w][4 * g4 + i];
#pragma unroll
    for (int nf2 = 0; nf2 < 8; ++nf2) {
      long row = (long)b * L + q0 + 16 * w + 4 * g4 + i;
      Y[row * 2048 + h * 128 + 16 * nf2 + r16] = f2bf(o[nf2][i] * linv);
    }
  }
}

// ---------------------------------------------------------------------------
extern "C" void kernel_launch(void* const* d_in, const int* in_sizes, int n_in,
                              void* d_out, int out_size, void* d_ws,
                              size_t ws_size, hipStream_t stream) {
  const float* x = (const float*)d_in[0];
  const float* wa = (const float*)d_in[1];
  const float* wp = (const float*)d_in[2];
  float* out = (float*)d_out;
  const int B = 2, L = 2048, C = 2048;
  const int M = B * L;  // 4096

  unsigned short* xb = (unsigned short*)d_ws;
  unsigned short* wab = xb + (size_t)M * C;
  unsigned short* wpb = wab + (size_t)3 * C * C;
  unsigned short* Qb = wpb + (size_t)C * C;
  unsigned short* Kb = Qb + (size_t)M * C;
  unsigned short* Vb = Kb + (size_t)M * C;
  unsigned short* Yb = Vb + (size_t)M * C;

  const int n1 = M * C / 4;
  const int n2 = n1 + 3 * C * C / 4;
  const int n4 = n2 + C * C / 4;
  cast_all<<<2048, 256, 0, stream>>>(x, wa, wp, xb, wab, wpb, n1, n2, n4);

  // qkv: 128x256 4-phase BK=64, grid 24x32 = 768 blocks = exactly 3 rounds
  gemm8p<1><<<dim3(3 * C / 256, M / 128), 512, 0, stream>>>(
      xb, wab, nullptr, Qb, Kb, Vb, M, 3 * C, C, L);

  // attn: QBLK=64, 4 waves, 1024 blocks (2 blocks/CU)
  attn_fwd<<<1024, 256, 0, stream>>>(Qb, Kb, Vb, Yb, L);

  // proj: 2-phase 128^2, grid 512 blocks
  gemm_bt<0><<<(M / 128) * (C / 128), 256, 0, stream>>>(
      Yb, wpb, out, nullptr, nullptr, nullptr, M, C, C, L, C / 128);
}